// Round 2
// baseline (689.161 us; speedup 1.0000x reference)
//
#include <hip/hip_runtime.h>
#include <hip/hip_bf16.h>

// Bahdanau attention, MI355X. B=32, S=2048, H=1024, HL=2048.
// d_in: query[32,1,2048] keys[32,2048,1024] Wa_w[2048,1024] Wa_b[1024]
//       Ua_w[1024,1024] Ua_b[1024] Va_w[1024,1] Va_b[1]
// d_out: context[32,1,1024] ++ weights[32,1,2048]  (fp32)
// ws layout: qws 128KB | Ua^T bf16 2MB | partial scores 4MB | ctx partials 1MB (~7.4MB)
// R1 fix: partial scores split per wave-n-half ([32][16][2048]) — waves 0/2 and 1/3
// shared the same m-rows but different n-halves and raced on the same address.

typedef __attribute__((ext_vector_type(8))) short short8;
typedef __attribute__((ext_vector_type(4))) float floatx4;

__device__ __forceinline__ unsigned short f2bf(float f) {
    union { float f; unsigned int u; } c; c.f = f;
    unsigned int u = c.u + 0x7fffu + ((c.u >> 16) & 1u);  // RNE
    return (unsigned short)(u >> 16);
}

// ---- K1: q[b,h] = sum_d query[b,d]*Wa[d,h] + Wa_b[h] + Ua_b[h] (fp32 exact) ----
__global__ __launch_bounds__(256) void qproj_k(
    const float* __restrict__ query, const float* __restrict__ Wa,
    const float* __restrict__ Wab, const float* __restrict__ Uab,
    float* __restrict__ qws)
{
    __shared__ float qs[2048];
    __shared__ float red[4][64];
    const int tid = threadIdx.x;
    const int b = blockIdx.x, hc = blockIdx.y;
    #pragma unroll
    for (int i = 0; i < 8; i++) qs[tid + 256*i] = query[b*2048 + tid + 256*i];
    __syncthreads();
    const int h_l = tid & 63, dg = tid >> 6;
    const int h = hc*64 + h_l;
    float acc = 0.f;
    const float* wp = Wa + (size_t)(dg*512)*1024 + h;
    const float* qp = qs + dg*512;
    #pragma unroll 4
    for (int d = 0; d < 512; d++) acc += qp[d] * wp[(size_t)d*1024];
    red[dg][h_l] = acc;
    __syncthreads();
    if (tid < 64) {
        float r = red[0][tid] + red[1][tid] + red[2][tid] + red[3][tid];
        int hh = hc*64 + tid;
        qws[b*1024 + hh] = r + Wab[hh] + Uab[hh];
    }
}

// ---- K2: Ua^T bf16: uat[h][d] = bf16(Ua[d][h]) ----
__global__ __launch_bounds__(256) void uat_k(const float* __restrict__ Ua,
                                             unsigned short* __restrict__ uat)
{
    __shared__ unsigned short t[64][65];
    const int x = threadIdx.x & 63, yy = threadIdx.x >> 6;
    const int d0 = blockIdx.x*64, h0 = blockIdx.y*64;
    #pragma unroll
    for (int i = 0; i < 16; i++) {
        int y = yy*16 + i;
        t[y][x] = f2bf(Ua[(size_t)(d0+y)*1024 + h0 + x]);
    }
    __syncthreads();
    #pragma unroll
    for (int i = 0; i < 16; i++) {
        int y = yy*16 + i;
        uat[(size_t)(h0+y)*1024 + d0 + x] = t[x][y];
    }
}

// ---- K3: fused score GEMM: partial[b][ht2][s] = sum_{h in half-tile} Va[h]*tanh(q[b,h]+keys.Ua) ----
__global__ __launch_bounds__(256) void score_gemm(
    const float* __restrict__ keys,           // [32][2048][1024] fp32
    const unsigned short* __restrict__ uat,   // [1024][1024] bf16, [h][d]
    const float* __restrict__ qws,            // [32][1024]
    const float* __restrict__ Va,             // [1024]
    float* __restrict__ partial)              // [32][16][2048]
{
    // LDS: rows padded 32->40 bf16 (80B) so frag ds_read_b128 is only 2-way aliased (free)
    __shared__ unsigned short aS[128][40];
    __shared__ unsigned short bS[128][40];
    const int tid = threadIdx.x;
    const int b = blockIdx.z;
    const int s0 = blockIdx.x * 128;
    const int h0 = blockIdx.y * 128;
    const int lane = tid & 63, wave = tid >> 6;
    const int quad = lane >> 4, l15 = lane & 15;
    const int wm = (wave & 1) * 64, wn = (wave >> 1) * 64;

    floatx4 acc[4][4];
    #pragma unroll
    for (int i = 0; i < 4; i++)
        #pragma unroll
        for (int j = 0; j < 4; j++) acc[i][j] = (floatx4)0.0f;

    const float4* keys4 = reinterpret_cast<const float4*>(keys) + (size_t)(b*2048 + s0)*256;
    const uint4*  uat4  = reinterpret_cast<const uint4*>(uat) + (size_t)h0*128;

    for (int k0 = 0; k0 < 1024; k0 += 32) {
        // stage A: keys fp32 -> bf16 LDS [m][k]
        #pragma unroll
        for (int i = 0; i < 4; i++) {
            int f = tid + 256*i;
            int row = f >> 3, c4 = f & 7;
            float4 v = keys4[(size_t)row*256 + (k0 >> 2) + c4];
            ushort4 o;
            o.x = f2bf(v.x); o.y = f2bf(v.y); o.z = f2bf(v.z); o.w = f2bf(v.w);
            *reinterpret_cast<ushort4*>(&aS[row][c4*4]) = o;
        }
        // stage B: Ua^T bf16 -> LDS [n][k] (no transpose needed)
        #pragma unroll
        for (int i = 0; i < 2; i++) {
            int f = tid + 256*i;
            int row = f >> 2, c8 = f & 3;
            uint4 v = uat4[(size_t)row*128 + (k0 >> 3) + c8];
            *reinterpret_cast<uint4*>(&bS[row][c8*8]) = v;
        }
        __syncthreads();
        short8 af[4], bf8[4];
        #pragma unroll
        for (int i = 0; i < 4; i++)
            af[i] = *reinterpret_cast<const short8*>(&aS[wm + 16*i + l15][quad*8]);
        #pragma unroll
        for (int j = 0; j < 4; j++)
            bf8[j] = *reinterpret_cast<const short8*>(&bS[wn + 16*j + l15][quad*8]);
        #pragma unroll
        for (int i = 0; i < 4; i++)
            #pragma unroll
            for (int j = 0; j < 4; j++)
                acc[i][j] = __builtin_amdgcn_mfma_f32_16x16x32_bf16(af[i], bf8[j], acc[i][j], 0, 0, 0);
        __syncthreads();
    }

    // epilogue: p[s] = sum_n Va[n]*tanh(q[n]+k[s,n]); C-layout: n=lane&15, m=quad*4+reg
    float qv[4], vav[4];
    #pragma unroll
    for (int j = 0; j < 4; j++) {
        int n = h0 + wn + 16*j + l15;
        qv[j]  = qws[b*1024 + n];
        vav[j] = Va[n];
    }
    // each wave owns a distinct (h-tile, n-half) slot: no cross-wave write sharing
    const int slot = blockIdx.y * 2 + (wave >> 1);   // 0..15
    #pragma unroll
    for (int i = 0; i < 4; i++) {
        #pragma unroll
        for (int r = 0; r < 4; r++) {
            float p = 0.f;
            #pragma unroll
            for (int j = 0; j < 4; j++) {
                float x = qv[j] + acc[i][j][r];
                float e = __expf(2.f * x);                       // tanh = 1 - 2/(e^{2x}+1)
                float t = 1.f - 2.f * __builtin_amdgcn_rcpf(e + 1.f);
                p += vav[j] * t;
            }
            #pragma unroll
            for (int off = 1; off < 16; off <<= 1) p += __shfl_xor(p, off, 64);
            if (l15 == 0) {
                int m = wm + 16*i + quad*4 + r;
                partial[((size_t)b*16 + slot)*2048 + s0 + m] = p;
            }
        }
    }
}

// ---- K4: softmax over s per batch ----
__global__ __launch_bounds__(256) void softmax_k(const float* __restrict__ partial,
                                                 float* __restrict__ out_w)
{
    const int tid = threadIdx.x;
    const int b = blockIdx.x;
    __shared__ float wred[4], wred2[4];
    float sc[8];
    float mx = -3.0e38f;
    #pragma unroll
    for (int i = 0; i < 8; i++) {
        int s = tid + 256*i;
        float v = 0.f;
        #pragma unroll
        for (int ht = 0; ht < 16; ht++) v += partial[((size_t)b*16 + ht)*2048 + s];
        sc[i] = v; mx = fmaxf(mx, v);
    }
    #pragma unroll
    for (int off = 32; off >= 1; off >>= 1) mx = fmaxf(mx, __shfl_xor(mx, off, 64));
    if ((tid & 63) == 0) wred[tid >> 6] = mx;
    __syncthreads();
    mx = fmaxf(fmaxf(wred[0], wred[1]), fmaxf(wred[2], wred[3]));
    float e[8]; float lsum = 0.f;
    #pragma unroll
    for (int i = 0; i < 8; i++) { e[i] = __expf(sc[i] - mx); lsum += e[i]; }
    #pragma unroll
    for (int off = 32; off >= 1; off >>= 1) lsum += __shfl_xor(lsum, off, 64);
    if ((tid & 63) == 0) wred2[tid >> 6] = lsum;
    __syncthreads();
    float inv = 1.0f / (wred2[0] + wred2[1] + wred2[2] + wred2[3]);
    #pragma unroll
    for (int i = 0; i < 8; i++) out_w[b*2048 + tid + 256*i] = e[i] * inv;
}

// ---- K5: context partials: ctxp[b][sc][h] = sum_{s in chunk} w[s]*keys[b,s,h] ----
__global__ __launch_bounds__(256) void ctx_k(const float* __restrict__ keys,
                                             const float* __restrict__ w,
                                             float* __restrict__ ctxp)
{
    const int tid = threadIdx.x;
    const int b = blockIdx.x, sc = blockIdx.y;
    const float4* k4 = reinterpret_cast<const float4*>(keys) + (size_t)(b*2048 + sc*256)*256;
    const float* wp = w + b*2048 + sc*256;
    float4 a; a.x = a.y = a.z = a.w = 0.f;
    #pragma unroll 4
    for (int s = 0; s < 256; s++) {
        float wv = wp[s];
        float4 kv = k4[(size_t)s*256 + tid];
        a.x += wv*kv.x; a.y += wv*kv.y; a.z += wv*kv.z; a.w += wv*kv.w;
    }
    reinterpret_cast<float4*>(ctxp)[((size_t)b*8 + sc)*256 + tid] = a;
}

// ---- K6: reduce context partials ----
__global__ __launch_bounds__(256) void ctxsum_k(const float* __restrict__ ctxp,
                                                float* __restrict__ out)
{
    const int idx = blockIdx.x*256 + threadIdx.x;   // b*1024 + h
    const int b = idx >> 10, h = idx & 1023;
    float v = 0.f;
    #pragma unroll
    for (int sc = 0; sc < 8; sc++) v += ctxp[((size_t)b*8 + sc)*1024 + h];
    out[idx] = v;
}

extern "C" void kernel_launch(void* const* d_in, const int* in_sizes, int n_in,
                              void* d_out, int out_size, void* d_ws, size_t ws_size,
                              hipStream_t stream)
{
    const float* query = (const float*)d_in[0];
    const float* keys  = (const float*)d_in[1];
    const float* Wa_w  = (const float*)d_in[2];
    const float* Wa_b  = (const float*)d_in[3];
    const float* Ua_w  = (const float*)d_in[4];
    const float* Ua_b  = (const float*)d_in[5];
    const float* Va_w  = (const float*)d_in[6];
    // d_in[7] (Va_b) is a uniform shift on scores -> softmax-invariant; unused.

    char* ws = (char*)d_ws;
    float*          qws     = (float*)(ws);                                   // 131072 B
    unsigned short* uat     = (unsigned short*)(ws + 131072);                 // 2 MiB
    float*          partial = (float*)(ws + 131072 + 2097152);                // 4 MiB
    float*          ctxp    = (float*)(ws + 131072 + 2097152 + 4194304);      // 1 MiB

    float* out_ctx = (float*)d_out;          // [32*1024]
    float* out_w   = out_ctx + 32*1024;      // [32*2048]

    qproj_k  <<<dim3(32, 16),    256, 0, stream>>>(query, Wa_w, Wa_b, Ua_b, qws);
    uat_k    <<<dim3(16, 16),    256, 0, stream>>>(Ua_w, uat);
    score_gemm<<<dim3(16, 8, 32), 256, 0, stream>>>(keys, uat, qws, Va_w, partial);
    softmax_k<<<dim3(32),        256, 0, stream>>>(partial, out_w);
    ctx_k    <<<dim3(32, 8),     256, 0, stream>>>(keys, out_w, ctxp);
    ctxsum_k <<<dim3(128),       256, 0, stream>>>(ctxp, out_ctx);
}

// Round 4
// 677.690 us; speedup vs baseline: 1.0169x; 1.0169x over previous
//
#include <hip/hip_runtime.h>
#include <hip/hip_bf16.h>

// Bahdanau attention, MI355X. B=32, S=2048, H=1024, HL=2048.
// d_out: context[32,1,1024] ++ weights[32,1,2048]  (fp32)
//
// R4: fix the addrspace cast for __builtin_amdgcn_global_load_lds (pointer->
// pointer across address spaces is rejected; go through uintptr_t). Otherwise
// identical to R3: keys pre-converted to bf16, m97-style score GEMM with
// 16B global_load_lds staging + XOR-swizzled LDS, split ctx reduction.
//
// ws layout (fast): qws 128K | uat 2M | partial 4M | ctxp 2M | kb16 128M

typedef __attribute__((ext_vector_type(8))) short short8;
typedef __attribute__((ext_vector_type(4))) float floatx4;

typedef const __attribute__((address_space(1))) unsigned int gu32;
typedef __attribute__((address_space(3))) unsigned int lu32;

__device__ __forceinline__ unsigned short f2bf(float f) {
    union { float f; unsigned int u; } c; c.f = f;
    unsigned int u = c.u + 0x7fffu + ((c.u >> 16) & 1u);  // RNE
    return (unsigned short)(u >> 16);
}

// async global->LDS, 16B per lane; lane i's data lands at ldsbase + i*16.
// casts route through integers: pointer->pointer addrspace casts are rejected.
__device__ __forceinline__ void gld16(const unsigned short* g, unsigned short* l) {
    __builtin_amdgcn_global_load_lds(
        (gu32*)(uintptr_t)g,
        (lu32*)(unsigned int)(uintptr_t)l,   // low 32 bits of generic LDS addr = LDS offset
        16, 0, 0);
}

// ---- K1: q[b,h] = sum_d query[b,d]*Wa[d,h] + Wa_b[h] + Ua_b[h] (fp32 exact) ----
__global__ __launch_bounds__(256) void qproj_k(
    const float* __restrict__ query, const float* __restrict__ Wa,
    const float* __restrict__ Wab, const float* __restrict__ Uab,
    float* __restrict__ qws)
{
    __shared__ float qs[2048];
    __shared__ float red[4][64];
    const int tid = threadIdx.x;
    const int b = blockIdx.x, hc = blockIdx.y;
    #pragma unroll
    for (int i = 0; i < 8; i++) qs[tid + 256*i] = query[b*2048 + tid + 256*i];
    __syncthreads();
    const int h_l = tid & 63, dg = tid >> 6;
    const int h = hc*64 + h_l;
    float acc = 0.f;
    const float* wp = Wa + (size_t)(dg*512)*1024 + h;
    const float* qp = qs + dg*512;
    #pragma unroll 4
    for (int d = 0; d < 512; d++) acc += qp[d] * wp[(size_t)d*1024];
    red[dg][h_l] = acc;
    __syncthreads();
    if (tid < 64) {
        float r = red[0][tid] + red[1][tid] + red[2][tid] + red[3][tid];
        int hh = hc*64 + tid;
        qws[b*1024 + hh] = r + Wab[hh] + Uab[hh];
    }
}

// ---- K2: Ua^T bf16: uat[h][d] = bf16(Ua[d][h]) ----
__global__ __launch_bounds__(256) void uat_k(const float* __restrict__ Ua,
                                             unsigned short* __restrict__ uat)
{
    __shared__ unsigned short t[64][65];
    const int x = threadIdx.x & 63, yy = threadIdx.x >> 6;
    const int d0 = blockIdx.x*64, h0 = blockIdx.y*64;
    #pragma unroll
    for (int i = 0; i < 16; i++) {
        int y = yy*16 + i;
        t[y][x] = f2bf(Ua[(size_t)(d0+y)*1024 + h0 + x]);
    }
    __syncthreads();
    #pragma unroll
    for (int i = 0; i < 16; i++) {
        int y = yy*16 + i;
        uat[(size_t)(h0+y)*1024 + d0 + x] = t[x][y];
    }
}

// ---- K2b: keys fp32 -> bf16 (streaming) ----
__global__ __launch_bounds__(256) void kb16_k(const float4* __restrict__ in,
                                              ushort4* __restrict__ out)
{
    const int base = blockIdx.x*1024 + threadIdx.x;
    #pragma unroll
    for (int j = 0; j < 4; j++) {
        float4 v = in[base + 256*j];
        ushort4 o;
        o.x = f2bf(v.x); o.y = f2bf(v.y); o.z = f2bf(v.z); o.w = f2bf(v.w);
        out[base + 256*j] = o;
    }
}

// ---- K3 (fast): m97-style score GEMM, bf16 keys, global_load_lds staging ----
// LDS tile rows are 64B (32 bf16), 16B chunks XOR-swizzled: slot = chunk ^ ((row>>1)&3).
// Staging: lane l of instr c covers row c*16 + (l>>2), global chunk (l&3)^(((l>>2)>>1)&3)
//   -> per row the 4 lanes fetch a permutation of 64B contiguous global (coalesced),
//      and HW places lane l at ldsbase + l*16 = [row][slot] as required.
// Frag read banks (per quad): (l15&1)*16 + (quad^((l15>>1)&3))*4 -> all 8 groups, 2-way = free.
__global__ __launch_bounds__(256) void score_gemm_fast(
    const unsigned short* __restrict__ kb,    // [32][2048][1024] bf16
    const unsigned short* __restrict__ uat,   // [1024][1024] bf16 [h][d]
    const float* __restrict__ qws,            // [32][1024]
    const float* __restrict__ Va,             // [1024]
    float* __restrict__ partial)              // [32][16][2048]
{
    __shared__ unsigned short aS[128*32];     // 8KB
    __shared__ unsigned short bS[128*32];     // 8KB
    const int tid = threadIdx.x;
    const int b = blockIdx.z;
    const int s0 = blockIdx.x * 128;
    const int h0 = blockIdx.y * 128;
    const int lane = tid & 63, wave = tid >> 6;
    const int quad = lane >> 4, l15 = lane & 15;
    const int wm = (wave & 1) * 64, wn = (wave >> 1) * 64;

    const int srow = lane >> 2;                       // 0..15 within chunk
    const int schunk = (lane & 3) ^ ((srow >> 1) & 3);

    floatx4 acc[4][4];
    #pragma unroll
    for (int i = 0; i < 4; i++)
        #pragma unroll
        for (int j = 0; j < 4; j++) acc[i][j] = (floatx4)0.0f;

    const unsigned short* kbase = kb + (size_t)(b*2048 + s0)*1024;
    const unsigned short* ubase = uat + (size_t)h0*1024;
    // per-lane source offsets (k0 added in loop)
    const int c0 = wave*2, c1 = wave*2 + 1;
    const size_t aoff0 = (size_t)(c0*16 + srow)*1024 + schunk*8;
    const size_t aoff1 = (size_t)(c1*16 + srow)*1024 + schunk*8;

    for (int k0 = 0; k0 < 1024; k0 += 32) {
        gld16(kbase + aoff0 + k0, aS + c0*512);
        gld16(kbase + aoff1 + k0, aS + c1*512);
        gld16(ubase + aoff0 + k0, bS + c0*512);
        gld16(ubase + aoff1 + k0, bS + c1*512);
        __syncthreads();
        short8 af[4], bf8[4];
        #pragma unroll
        for (int i = 0; i < 4; i++) {
            int row = wm + 16*i + l15;
            af[i] = *reinterpret_cast<const short8*>(aS + row*32 + ((quad ^ ((row>>1)&3)) * 8));
        }
        #pragma unroll
        for (int j = 0; j < 4; j++) {
            int row = wn + 16*j + l15;
            bf8[j] = *reinterpret_cast<const short8*>(bS + row*32 + ((quad ^ ((row>>1)&3)) * 8));
        }
        #pragma unroll
        for (int i = 0; i < 4; i++)
            #pragma unroll
            for (int j = 0; j < 4; j++)
                acc[i][j] = __builtin_amdgcn_mfma_f32_16x16x32_bf16(af[i], bf8[j], acc[i][j], 0, 0, 0);
        __syncthreads();
    }

    // epilogue: p[s] = sum_n Va[n]*tanh(q[n]+k[s,n]); C-layout: n=lane&15, m=quad*4+reg
    float qv[4], vav[4];
    #pragma unroll
    for (int j = 0; j < 4; j++) {
        int n = h0 + wn + 16*j + l15;
        qv[j]  = qws[b*1024 + n];
        vav[j] = Va[n];
    }
    const int slot = blockIdx.y * 2 + (wave >> 1);   // 0..15, unique per (h-tile, n-half)
    #pragma unroll
    for (int i = 0; i < 4; i++) {
        #pragma unroll
        for (int r = 0; r < 4; r++) {
            float p = 0.f;
            #pragma unroll
            for (int j = 0; j < 4; j++) {
                float x = qv[j] + acc[i][j][r];
                float e = __expf(2.f * x);                       // tanh = 1 - 2/(e^{2x}+1)
                float t = 1.f - 2.f * __builtin_amdgcn_rcpf(e + 1.f);
                p += vav[j] * t;
            }
            #pragma unroll
            for (int off = 1; off < 16; off <<= 1) p += __shfl_xor(p, off, 64);
            if (l15 == 0) {
                int m = wm + 16*i + quad*4 + r;
                partial[((size_t)b*16 + slot)*2048 + s0 + m] = p;
            }
        }
    }
}

// ---- K3 (fallback, proven R2 path): fp32 keys, in-loop convert ----
__global__ __launch_bounds__(256) void score_gemm(
    const float* __restrict__ keys, const unsigned short* __restrict__ uat,
    const float* __restrict__ qws, const float* __restrict__ Va,
    float* __restrict__ partial)
{
    __shared__ unsigned short aS[128][40];
    __shared__ unsigned short bS[128][40];
    const int tid = threadIdx.x;
    const int b = blockIdx.z;
    const int s0 = blockIdx.x * 128;
    const int h0 = blockIdx.y * 128;
    const int lane = tid & 63, wave = tid >> 6;
    const int quad = lane >> 4, l15 = lane & 15;
    const int wm = (wave & 1) * 64, wn = (wave >> 1) * 64;

    floatx4 acc[4][4];
    #pragma unroll
    for (int i = 0; i < 4; i++)
        #pragma unroll
        for (int j = 0; j < 4; j++) acc[i][j] = (floatx4)0.0f;

    const float4* keys4 = reinterpret_cast<const float4*>(keys) + (size_t)(b*2048 + s0)*256;
    const uint4*  uat4  = reinterpret_cast<const uint4*>(uat) + (size_t)h0*128;

    for (int k0 = 0; k0 < 1024; k0 += 32) {
        #pragma unroll
        for (int i = 0; i < 4; i++) {
            int f = tid + 256*i;
            int row = f >> 3, c4 = f & 7;
            float4 v = keys4[(size_t)row*256 + (k0 >> 2) + c4];
            ushort4 o;
            o.x = f2bf(v.x); o.y = f2bf(v.y); o.z = f2bf(v.z); o.w = f2bf(v.w);
            *reinterpret_cast<ushort4*>(&aS[row][c4*4]) = o;
        }
        #pragma unroll
        for (int i = 0; i < 2; i++) {
            int f = tid + 256*i;
            int row = f >> 2, c8 = f & 3;
            uint4 v = uat4[(size_t)row*128 + (k0 >> 3) + c8];
            *reinterpret_cast<uint4*>(&bS[row][c8*8]) = v;
        }
        __syncthreads();
        short8 af[4], bf8[4];
        #pragma unroll
        for (int i = 0; i < 4; i++)
            af[i] = *reinterpret_cast<const short8*>(&aS[wm + 16*i + l15][quad*8]);
        #pragma unroll
        for (int j = 0; j < 4; j++)
            bf8[j] = *reinterpret_cast<const short8*>(&bS[wn + 16*j + l15][quad*8]);
        #pragma unroll
        for (int i = 0; i < 4; i++)
            #pragma unroll
            for (int j = 0; j < 4; j++)
                acc[i][j] = __builtin_amdgcn_mfma_f32_16x16x32_bf16(af[i], bf8[j], acc[i][j], 0, 0, 0);
        __syncthreads();
    }

    float qv[4], vav[4];
    #pragma unroll
    for (int j = 0; j < 4; j++) {
        int n = h0 + wn + 16*j + l15;
        qv[j]  = qws[b*1024 + n];
        vav[j] = Va[n];
    }
    const int slot = blockIdx.y * 2 + (wave >> 1);
    #pragma unroll
    for (int i = 0; i < 4; i++) {
        #pragma unroll
        for (int r = 0; r < 4; r++) {
            float p = 0.f;
            #pragma unroll
            for (int j = 0; j < 4; j++) {
                float x = qv[j] + acc[i][j][r];
                float e = __expf(2.f * x);
                float t = 1.f - 2.f * __builtin_amdgcn_rcpf(e + 1.f);
                p += vav[j] * t;
            }
            #pragma unroll
            for (int off = 1; off < 16; off <<= 1) p += __shfl_xor(p, off, 64);
            if (l15 == 0) {
                int m = wm + 16*i + quad*4 + r;
                partial[((size_t)b*16 + slot)*2048 + s0 + m] = p;
            }
        }
    }
}

// ---- K4: softmax over s per batch ----
__global__ __launch_bounds__(256) void softmax_k(const float* __restrict__ partial,
                                                 float* __restrict__ out_w)
{
    const int tid = threadIdx.x;
    const int b = blockIdx.x;
    __shared__ float wred[4], wred2[4];
    float sc[8];
    float mx = -3.0e38f;
    #pragma unroll
    for (int i = 0; i < 8; i++) {
        int s = tid + 256*i;
        float v = 0.f;
        #pragma unroll
        for (int ht = 0; ht < 16; ht++) v += partial[((size_t)b*16 + ht)*2048 + s];
        sc[i] = v; mx = fmaxf(mx, v);
    }
    #pragma unroll
    for (int off = 32; off >= 1; off >>= 1) mx = fmaxf(mx, __shfl_xor(mx, off, 64));
    if ((tid & 63) == 0) wred[tid >> 6] = mx;
    __syncthreads();
    mx = fmaxf(fmaxf(wred[0], wred[1]), fmaxf(wred[2], wred[3]));
    float e[8]; float lsum = 0.f;
    #pragma unroll
    for (int i = 0; i < 8; i++) { e[i] = __expf(sc[i] - mx); lsum += e[i]; }
    #pragma unroll
    for (int off = 32; off >= 1; off >>= 1) lsum += __shfl_xor(lsum, off, 64);
    if ((tid & 63) == 0) wred2[tid >> 6] = lsum;
    __syncthreads();
    float inv = 1.0f / (wred2[0] + wred2[1] + wred2[2] + wred2[3]);
    #pragma unroll
    for (int i = 0; i < 8; i++) out_w[b*2048 + tid + 256*i] = e[i] * inv;
}

// ---- K5: context partials over s-chunks ----
__global__ __launch_bounds__(256) void ctx_k(const float* __restrict__ keys,
                                             const float* __restrict__ w,
                                             float* __restrict__ ctxp, int sper)
{
    const int tid = threadIdx.x;
    const int b = blockIdx.x, sc = blockIdx.y;
    const float4* k4 = reinterpret_cast<const float4*>(keys) + (size_t)(b*2048 + sc*sper)*256;
    const float* wp = w + b*2048 + sc*sper;
    float4 a; a.x = a.y = a.z = a.w = 0.f;
    #pragma unroll 4
    for (int s = 0; s < sper; s++) {
        float wv = wp[s];
        float4 kv = k4[(size_t)s*256 + tid];
        a.x += wv*kv.x; a.y += wv*kv.y; a.z += wv*kv.z; a.w += wv*kv.w;
    }
    reinterpret_cast<float4*>(ctxp)[((size_t)b*gridDim.y + sc)*256 + tid] = a;
}

// ---- K6: reduce context partials ----
__global__ __launch_bounds__(256) void ctxsum_k(const float* __restrict__ ctxp,
                                                float* __restrict__ out, int nc)
{
    const int idx = blockIdx.x*256 + threadIdx.x;   // b*1024 + h
    const int b = idx >> 10, h = idx & 1023;
    float v = 0.f;
    for (int s = 0; s < nc; s++) v += ctxp[((size_t)b*nc + s)*1024 + h];
    out[idx] = v;
}

extern "C" void kernel_launch(void* const* d_in, const int* in_sizes, int n_in,
                              void* d_out, int out_size, void* d_ws, size_t ws_size,
                              hipStream_t stream)
{
    const float* query = (const float*)d_in[0];
    const float* keys  = (const float*)d_in[1];
    const float* Wa_w  = (const float*)d_in[2];
    const float* Wa_b  = (const float*)d_in[3];
    const float* Ua_w  = (const float*)d_in[4];
    const float* Ua_b  = (const float*)d_in[5];
    const float* Va_w  = (const float*)d_in[6];
    // d_in[7] (Va_b) is a uniform shift on scores -> softmax-invariant; unused.

    char* ws = (char*)d_ws;
    float*          qws     = (float*)(ws);                       // 128 KiB
    unsigned short* uat     = (unsigned short*)(ws + (131072));   // 2 MiB
    float*          partial = (float*)(ws + (131072 + 2097152));  // 4 MiB
    float*          ctxp    = (float*)(ws + (131072 + 2097152 + 4194304)); // <=2 MiB
    unsigned short* kb      = (unsigned short*)(ws + (131072 + 2097152 + 4194304 + 2097152));
    const size_t NEED_FAST = 131072ull + 2097152 + 4194304 + 2097152 + 134217728;

    float* out_ctx = (float*)d_out;          // [32*1024]
    float* out_w   = out_ctx + 32*1024;      // [32*2048]

    qproj_k <<<dim3(32, 16), 256, 0, stream>>>(query, Wa_w, Wa_b, Ua_b, qws);
    uat_k   <<<dim3(16, 16), 256, 0, stream>>>(Ua_w, uat);

    if (ws_size >= NEED_FAST) {
        kb16_k         <<<dim3(16384),     256, 0, stream>>>((const float4*)keys, (ushort4*)kb);
        score_gemm_fast<<<dim3(16, 8, 32), 256, 0, stream>>>(kb, uat, qws, Va_w, partial);
        softmax_k      <<<dim3(32),        256, 0, stream>>>(partial, out_w);
        ctx_k          <<<dim3(32, 16),    256, 0, stream>>>(keys, out_w, ctxp, 128);
        ctxsum_k       <<<dim3(128),       256, 0, stream>>>(ctxp, out_ctx, 16);
    } else {
        score_gemm     <<<dim3(16, 8, 32), 256, 0, stream>>>(keys, uat, qws, Va_w, partial);
        softmax_k      <<<dim3(32),        256, 0, stream>>>(partial, out_w);
        ctx_k          <<<dim3(32, 8),     256, 0, stream>>>(keys, out_w, ctxp, 256);
        ctxsum_k       <<<dim3(128),       256, 0, stream>>>(ctxp, out_ctx, 8);
    }
}

// Round 5
// 659.373 us; speedup vs baseline: 1.0452x; 1.0278x over previous
//
#include <hip/hip_runtime.h>
#include <hip/hip_bf16.h>

// Bahdanau attention, MI355X. B=32, S=2048, H=1024, HL=2048.
// d_out: context[32,1,1024] ++ weights[32,1,2048]  (fp32)
//
// R5: kb16 pre-pass deleted — fp32->bf16 conversion fused into score GEMM
// A-staging (float4 load + pk-cvt + swizzled ds_write_b128; B stays async
// global_load_lds). qproj rewritten with float4 Wa loads (128 iters, 4x ILP).
//
// ws layout: qws 128K | uat 2M | partial 4M | ctxp 2M  (~8.3MB)

typedef __attribute__((ext_vector_type(8))) short short8;
typedef __attribute__((ext_vector_type(4))) float floatx4;

typedef const __attribute__((address_space(1))) unsigned int gu32;
typedef __attribute__((address_space(3))) unsigned int lu32;

__device__ __forceinline__ unsigned short f2bf(float f) {
    union { float f; unsigned int u; } c; c.f = f;
    unsigned int u = c.u + 0x7fffu + ((c.u >> 16) & 1u);  // RNE
    return (unsigned short)(u >> 16);
}

// two fp32 -> packed bf16 pair (lo in bits 0..15), RNE either way
__device__ __forceinline__ unsigned int f2bf2(float lo, float hi) {
#if __has_builtin(__builtin_amdgcn_cvt_pk_bf16_f32)
    auto r = __builtin_amdgcn_cvt_pk_bf16_f32(lo, hi);
    unsigned int u; __builtin_memcpy(&u, &r, 4);
    return u;
#else
    return (unsigned int)f2bf(lo) | ((unsigned int)f2bf(hi) << 16);
#endif
}

// async global->LDS, 16B per lane; lane i's data lands at ldsbase + i*16.
__device__ __forceinline__ void gld16(const unsigned short* g, unsigned short* l) {
    __builtin_amdgcn_global_load_lds(
        (gu32*)(uintptr_t)g,
        (lu32*)(unsigned int)(uintptr_t)l,
        16, 0, 0);
}

// ---- K1: q[b,h] = sum_d query[b,d]*Wa[d,h] + Wa_b[h] + Ua_b[h] (fp32 exact) ----
// 256 thr = 16 h-quads x 16 d-groups; float4 Wa loads; 128 iters/thread.
__global__ __launch_bounds__(256) void qproj_k(
    const float* __restrict__ query, const float* __restrict__ Wa,
    const float* __restrict__ Wab, const float* __restrict__ Uab,
    float* __restrict__ qws)
{
    __shared__ float qs[2048];
    __shared__ float red[16*64];
    const int tid = threadIdx.x;
    const int b = blockIdx.x, hc = blockIdx.y;
    #pragma unroll
    for (int i = 0; i < 8; i++) qs[tid + 256*i] = query[b*2048 + tid + 256*i];
    __syncthreads();
    const int hq = tid & 15;      // h-quad within 64-h tile
    const int dg = tid >> 4;      // d-group (128 d each)
    const float4* wp = reinterpret_cast<const float4*>(Wa + (size_t)(dg*128)*1024 + hc*64 + hq*4);
    const float* qp = qs + dg*128;
    float4 a0; a0.x = a0.y = a0.z = a0.w = 0.f;
    float4 a1; a1.x = a1.y = a1.z = a1.w = 0.f;
    #pragma unroll 4
    for (int d = 0; d < 128; d += 2) {
        float q0 = qp[d], q1 = qp[d+1];
        float4 w0 = wp[(size_t)d*256];
        float4 w1 = wp[(size_t)(d+1)*256];
        a0.x += q0*w0.x; a0.y += q0*w0.y; a0.z += q0*w0.z; a0.w += q0*w0.w;
        a1.x += q1*w1.x; a1.y += q1*w1.y; a1.z += q1*w1.z; a1.w += q1*w1.w;
    }
    a0.x += a1.x; a0.y += a1.y; a0.z += a1.z; a0.w += a1.w;
    *reinterpret_cast<float4*>(red + dg*64 + hq*4) = a0;
    __syncthreads();
    if (tid < 64) {
        float v = 0.f;
        #pragma unroll
        for (int g = 0; g < 16; g++) v += red[g*64 + tid];
        int hh = hc*64 + tid;
        qws[b*1024 + hh] = v + Wab[hh] + Uab[hh];
    }
}

// ---- K2: Ua^T bf16: uat[h][d] = bf16(Ua[d][h]) ----
__global__ __launch_bounds__(256) void uat_k(const float* __restrict__ Ua,
                                             unsigned short* __restrict__ uat)
{
    __shared__ unsigned short t[64][65];
    const int x = threadIdx.x & 63, yy = threadIdx.x >> 6;
    const int d0 = blockIdx.x*64, h0 = blockIdx.y*64;
    #pragma unroll
    for (int i = 0; i < 16; i++) {
        int y = yy*16 + i;
        t[y][x] = f2bf(Ua[(size_t)(d0+y)*1024 + h0 + x]);
    }
    __syncthreads();
    #pragma unroll
    for (int i = 0; i < 16; i++) {
        int y = yy*16 + i;
        uat[(size_t)(h0+y)*1024 + d0 + x] = t[x][y];
    }
}

// ---- K3: fused score GEMM, fp32 keys converted in A-staging ----
// LDS rows 64B (32 bf16), 16B chunks XOR-swizzled: slot = chunk ^ ((row>>1)&3).
// A: float4 x2 load -> 4x pk-cvt -> ds_write_b128 at [row][slot].  Per
// quarter-wave the writes land 2 lanes per 4-bank group -> conflict-free.
// B (already bf16): async gld16, lane l -> ldsbase + l*16, fetch order chosen
// so chunk c lands at slot c^((row>>1)&3).
// Frag reads (proven R4, 0 conflicts): aS + row*32 + (quad^((row>>1)&3))*8.
__global__ __launch_bounds__(256) void score_gemm_fast(
    const float* __restrict__ keys,           // [32][2048][1024] fp32
    const unsigned short* __restrict__ uat,   // [1024][1024] bf16 [h][d]
    const float* __restrict__ qws,            // [32][1024]
    const float* __restrict__ Va,             // [1024]
    float* __restrict__ partial)              // [32][16][2048]
{
    __shared__ unsigned short aS[128*32];     // 8KB
    __shared__ unsigned short bS[128*32];     // 8KB
    const int tid = threadIdx.x;
    const int b = blockIdx.z;
    const int s0 = blockIdx.x * 128;
    const int h0 = blockIdx.y * 128;
    const int lane = tid & 63, wave = tid >> 6;
    const int quad = lane >> 4, l15 = lane & 15;
    const int wm = (wave & 1) * 64, wn = (wave >> 1) * 64;

    const int srow = lane >> 2;                       // B-staging row-within-chunk
    const int schunk = (lane & 3) ^ ((srow >> 1) & 3);

    floatx4 acc[4][4];
    #pragma unroll
    for (int i = 0; i < 4; i++)
        #pragma unroll
        for (int j = 0; j < 4; j++) acc[i][j] = (floatx4)0.0f;

    const float* kA = keys + (size_t)(b*2048 + s0)*1024;
    const unsigned short* ubase = uat + (size_t)h0*1024;
    const int c0 = wave*2, c1 = wave*2 + 1;
    const size_t boff0 = (size_t)(c0*16 + srow)*1024 + schunk*8;
    const size_t boff1 = (size_t)(c1*16 + srow)*1024 + schunk*8;

    // A-staging constants: f = tid + 256*i -> row = f>>2 (0..127), c = f&3
    const int arow0 = tid >> 2, ac = tid & 3;

    for (int k0 = 0; k0 < 1024; k0 += 32) {
        // B: async bf16 staging (2 instrs)
        gld16(ubase + boff0 + k0, bS + c0*512);
        gld16(ubase + boff1 + k0, bS + c1*512);
        // A: fp32 load + convert + swizzled write (2 iters of 64 rows)
        #pragma unroll
        for (int i = 0; i < 2; i++) {
            int row = arow0 + 64*i;
            int sl  = ac ^ ((row >> 1) & 3);
            const float* gp = kA + (size_t)row*1024 + k0 + ac*8;
            float4 v0 = *reinterpret_cast<const float4*>(gp);
            float4 v1 = *reinterpret_cast<const float4*>(gp + 4);
            uint4 w;
            w.x = f2bf2(v0.x, v0.y); w.y = f2bf2(v0.z, v0.w);
            w.z = f2bf2(v1.x, v1.y); w.w = f2bf2(v1.z, v1.w);
            *reinterpret_cast<uint4*>(aS + row*32 + sl*8) = w;
        }
        __syncthreads();
        short8 af[4], bf8[4];
        #pragma unroll
        for (int i = 0; i < 4; i++) {
            int row = wm + 16*i + l15;
            af[i] = *reinterpret_cast<const short8*>(aS + row*32 + ((quad ^ ((row>>1)&3)) * 8));
        }
        #pragma unroll
        for (int j = 0; j < 4; j++) {
            int row = wn + 16*j + l15;
            bf8[j] = *reinterpret_cast<const short8*>(bS + row*32 + ((quad ^ ((row>>1)&3)) * 8));
        }
        #pragma unroll
        for (int i = 0; i < 4; i++)
            #pragma unroll
            for (int j = 0; j < 4; j++)
                acc[i][j] = __builtin_amdgcn_mfma_f32_16x16x32_bf16(af[i], bf8[j], acc[i][j], 0, 0, 0);
        __syncthreads();
    }

    // epilogue: p[s] = sum_n Va[n]*tanh(q[n]+k[s,n]); C-layout: n=lane&15, m=quad*4+reg
    float qv[4], vav[4];
    #pragma unroll
    for (int j = 0; j < 4; j++) {
        int n = h0 + wn + 16*j + l15;
        qv[j]  = qws[b*1024 + n];
        vav[j] = Va[n];
    }
    const int slot = blockIdx.y * 2 + (wave >> 1);   // unique per (h-tile, n-half)
    #pragma unroll
    for (int i = 0; i < 4; i++) {
        #pragma unroll
        for (int r = 0; r < 4; r++) {
            float p = 0.f;
            #pragma unroll
            for (int j = 0; j < 4; j++) {
                float x = qv[j] + acc[i][j][r];
                float e = __expf(2.f * x);                       // tanh = 1 - 2/(e^{2x}+1)
                float t = 1.f - 2.f * __builtin_amdgcn_rcpf(e + 1.f);
                p += vav[j] * t;
            }
            #pragma unroll
            for (int off = 1; off < 16; off <<= 1) p += __shfl_xor(p, off, 64);
            if (l15 == 0) {
                int m = wm + 16*i + quad*4 + r;
                partial[((size_t)b*16 + slot)*2048 + s0 + m] = p;
            }
        }
    }
}

// ---- K4: softmax over s per batch ----
__global__ __launch_bounds__(256) void softmax_k(const float* __restrict__ partial,
                                                 float* __restrict__ out_w)
{
    const int tid = threadIdx.x;
    const int b = blockIdx.x;
    __shared__ float wred[4], wred2[4];
    float sc[8];
    float mx = -3.0e38f;
    #pragma unroll
    for (int i = 0; i < 8; i++) {
        int s = tid + 256*i;
        float v = 0.f;
        #pragma unroll
        for (int ht = 0; ht < 16; ht++) v += partial[((size_t)b*16 + ht)*2048 + s];
        sc[i] = v; mx = fmaxf(mx, v);
    }
    #pragma unroll
    for (int off = 32; off >= 1; off >>= 1) mx = fmaxf(mx, __shfl_xor(mx, off, 64));
    if ((tid & 63) == 0) wred[tid >> 6] = mx;
    __syncthreads();
    mx = fmaxf(fmaxf(wred[0], wred[1]), fmaxf(wred[2], wred[3]));
    float e[8]; float lsum = 0.f;
    #pragma unroll
    for (int i = 0; i < 8; i++) { e[i] = __expf(sc[i] - mx); lsum += e[i]; }
    #pragma unroll
    for (int off = 32; off >= 1; off >>= 1) lsum += __shfl_xor(lsum, off, 64);
    if ((tid & 63) == 0) wred2[tid >> 6] = lsum;
    __syncthreads();
    float inv = 1.0f / (wred2[0] + wred2[1] + wred2[2] + wred2[3]);
    #pragma unroll
    for (int i = 0; i < 8; i++) out_w[b*2048 + tid + 256*i] = e[i] * inv;
}

// ---- K5: context partials over s-chunks ----
__global__ __launch_bounds__(256) void ctx_k(const float* __restrict__ keys,
                                             const float* __restrict__ w,
                                             float* __restrict__ ctxp, int sper)
{
    const int tid = threadIdx.x;
    const int b = blockIdx.x, sc = blockIdx.y;
    const float4* k4 = reinterpret_cast<const float4*>(keys) + (size_t)(b*2048 + sc*sper)*256;
    const float* wp = w + b*2048 + sc*sper;
    float4 a; a.x = a.y = a.z = a.w = 0.f;
    #pragma unroll 4
    for (int s = 0; s < sper; s++) {
        float wv = wp[s];
        float4 kv = k4[(size_t)s*256 + tid];
        a.x += wv*kv.x; a.y += wv*kv.y; a.z += wv*kv.z; a.w += wv*kv.w;
    }
    reinterpret_cast<float4*>(ctxp)[((size_t)b*gridDim.y + sc)*256 + tid] = a;
}

// ---- K6: reduce context partials ----
__global__ __launch_bounds__(256) void ctxsum_k(const float* __restrict__ ctxp,
                                                float* __restrict__ out, int nc)
{
    const int idx = blockIdx.x*256 + threadIdx.x;   // b*1024 + h
    const int b = idx >> 10, h = idx & 1023;
    float v = 0.f;
    for (int s = 0; s < nc; s++) v += ctxp[((size_t)b*nc + s)*1024 + h];
    out[idx] = v;
}

extern "C" void kernel_launch(void* const* d_in, const int* in_sizes, int n_in,
                              void* d_out, int out_size, void* d_ws, size_t ws_size,
                              hipStream_t stream)
{
    const float* query = (const float*)d_in[0];
    const float* keys  = (const float*)d_in[1];
    const float* Wa_w  = (const float*)d_in[2];
    const float* Wa_b  = (const float*)d_in[3];
    const float* Ua_w  = (const float*)d_in[4];
    const float* Ua_b  = (const float*)d_in[5];
    const float* Va_w  = (const float*)d_in[6];
    // d_in[7] (Va_b) is a uniform shift on scores -> softmax-invariant; unused.

    char* ws = (char*)d_ws;
    float*          qws     = (float*)(ws);                       // 128 KiB
    unsigned short* uat     = (unsigned short*)(ws + (131072));   // 2 MiB
    float*          partial = (float*)(ws + (131072 + 2097152));  // 4 MiB
    float*          ctxp    = (float*)(ws + (131072 + 2097152 + 4194304)); // 2 MiB

    float* out_ctx = (float*)d_out;          // [32*1024]
    float* out_w   = out_ctx + 32*1024;      // [32*2048]

    qproj_k        <<<dim3(32, 16),    256, 0, stream>>>(query, Wa_w, Wa_b, Ua_b, qws);
    uat_k          <<<dim3(16, 16),    256, 0, stream>>>(Ua_w, uat);
    score_gemm_fast<<<dim3(16, 8, 32), 256, 0, stream>>>(keys, uat, qws, Va_w, partial);
    softmax_k      <<<dim3(32),        256, 0, stream>>>(partial, out_w);
    ctx_k          <<<dim3(32, 16),    256, 0, stream>>>(keys, out_w, ctxp, 128);
    ctxsum_k       <<<dim3(128),       256, 0, stream>>>(ctxp, out_ctx, 16);
}